// Round 11
// baseline (249.302 us; speedup 1.0000x reference)
//
#include <hip/hip_runtime.h>
#include <stdint.h>

// B=4, C=256, H=W=64, N=4096, CQK=16, Ktot=C*9=2304
// ws layout:
//   qT  [4][4096][64] bf16   @ 0        (2 MiB)  slots0-31=[qh|qh], 32-63=[ql|0], q pre-scaled by log2(e)
//   kT  [4][4096][32] bf16   @ 2 MiB    (1 MiB)  slots0-15=kh, 16-31=kl (residual)
//   Vb  [4][256][4096] bf16  @ 3 MiB    (8 MiB)
//   W2v [256][2304] bf16     @ 11 MiB   (1152 KiB)   k-order: (ci>>6)*576 + tap*64 + (ci&63)
//   W2q [16][2304]  bf16     @ +1179648 (72 KiB)
//   W2k [16][2304]  bf16     @ +73728   (72 KiB)

typedef __bf16 bf16;
typedef bf16 bf16x8 __attribute__((ext_vector_type(8)));
typedef float f32x4 __attribute__((ext_vector_type(4)));

#define DEV static __device__ __forceinline__

DEV f32x4 mfma16(bf16x8 a, bf16x8 b, f32x4 c) {
  return __builtin_amdgcn_mfma_f32_16x16x32_bf16(a, b, c, 0, 0, 0);
}

// ===================== weight pack (all 3 tensors, one launch) =====================
__global__ void pack_all_kernel(const float* __restrict__ wv, const float* __restrict__ wq,
                                const float* __restrict__ wk, bf16* __restrict__ W2v,
                                bf16* __restrict__ W2q, bf16* __restrict__ W2k) {
  int idx = blockIdx.x * 256 + threadIdx.x;
  if (idx >= 663552) return;
  const float* src;
  bf16* dst;
  int rel;
  if (idx < 589824)      { src = wv; dst = W2v; rel = idx; }
  else if (idx < 626688) { src = wq; dst = W2q; rel = idx - 589824; }
  else                   { src = wk; dst = W2k; rel = idx - 626688; }
  int o = rel / 2304, r = rel - o * 2304;
  int ci = r / 9, tap = r - ci * 9;
  int kk = (ci >> 6) * 576 + tap * 64 + (ci & 63);
  dst[o * 2304 + kk] = (bf16)src[rel];
}

// ===================== conv q (O=16, stages x) =====================
// grid 256 = b*h; 4 waves, wave wv -> w-cols [16wv,16wv+16)
__global__ __launch_bounds__(256) void conv_q_kernel(
    const float* __restrict__ img, const bf16* __restrict__ W2,
    const float* __restrict__ bias, bf16* __restrict__ qT) {
  __shared__ __align__(16) bf16 sm[3 * 66 * 64];
  const int t = threadIdx.x;
  const int lane = t & 63, wv = t >> 6;
  const int g = lane >> 4, ln = lane & 15;
  const int b = blockIdx.x >> 6;
  const int h = blockIdx.x & 63;
  f32x4 acc = {0.f, 0.f, 0.f, 0.f};
  for (int chunk = 0; chunk < 4; ++chunk) {
    __syncthreads();
    // stage: halo zeros + 3x64x64 tile (fp32 -> bf16, swizzled)
    for (int idx = t; idx < 384; idx += 256) {
      int dh = idx >> 7, rr = idx & 127;
      int cl = rr & 63, wH = (rr >> 6) ? 65 : 0;
      uint32_t bo = ((((dh * 66 + wH) << 6) + cl) << 1) ^ ((wH & 7) << 4);
      *(bf16*)((char*)sm + bo) = (bf16)0.f;
    }
    {
      const int wg = t & 15, clp = t >> 4;
      for (int dh = 0; dh < 3; ++dh) {
        int hh = h + dh - 1;
        bool ok = (hh >= 0) && (hh < 64);
        for (int p = 0; p < 4; ++p) {
          int cl = (p << 4) + clp;
          int w0 = wg << 2;
          float4 xv = make_float4(0.f, 0.f, 0.f, 0.f);
          if (ok) xv = *(const float4*)&img[((((size_t)b << 8) + (chunk << 6) + cl) * 64 + hh) * 64 + w0];
          const float xs[4] = {xv.x, xv.y, xv.z, xv.w};
#pragma unroll
          for (int q4 = 0; q4 < 4; ++q4) {
            int wH = w0 + q4 + 1;
            uint32_t bo = ((((dh * 66 + wH) << 6) + cl) << 1) ^ ((wH & 7) << 4);
            *(bf16*)((char*)sm + bo) = (bf16)xs[q4];
          }
        }
      }
    }
    __syncthreads();
#pragma unroll
    for (int ks = 0; ks < 18; ++ks) {
      const int tap = ks >> 1, clb = (ks & 1) << 5;
      const int kh = tap / 3, kw = tap - kh * 3;
      const int wH = (wv << 4) + ln + kw;
      uint32_t bo = ((((kh * 66 + wH) << 6) + clb + (g << 3)) << 1) ^ ((wH & 7) << 4);
      bf16x8 bfr = *(const bf16x8*)((char*)sm + bo);
      bf16x8 afr = *(const bf16x8*)&W2[(size_t)ln * 2304 + chunk * 576 + (ks << 5) + (g << 3)];
      acc = mfma16(afr, bfr, acc);
    }
  }
  const int p = (h << 6) + (wv << 4) + ln;
#pragma unroll
  for (int r = 0; r < 4; ++r) {
    int o = (g << 2) + r;
    float val = (acc[r] + bias[o]) * 1.4426950408889634f;   // log2(e): softmax via exp2
    bf16* drow = qT + (((size_t)b << 12) + p) * 64;
    bf16 hi = (bf16)val;
    drow[o] = hi;
    drow[16 + o] = hi;                       // B1 = [qh|qh]
    drow[32 + o] = (bf16)(val - (float)hi);  // B2 = [ql|0]
    drow[48 + o] = (bf16)0.f;
  }
}

// ===================== conv v + k fused (stages y ONCE) =====================
// grid 256 = b*h, 512 threads (8 waves). Wave wv: v-outputs [32wv, 32wv+32) over all
// 64 w-pixels; waves 0-3 additionally compute k (16 o) for pixel-quarter wf=wv using
// the bfr they already loaded. Removes r10's oh-split staging duplication AND the
// entire k-mode staging pass.
__global__ __launch_bounds__(512) void conv_vk_kernel(
    const float* __restrict__ img, const bf16* __restrict__ W2v,
    const bf16* __restrict__ W2k, const float* __restrict__ bv,
    const float* __restrict__ bk, bf16* __restrict__ Vb, bf16* __restrict__ kTo) {
  __shared__ __align__(16) bf16 sm[3 * 66 * 64];
  const int t = threadIdx.x;
  const int lane = t & 63, wv = t >> 6;     // 8 waves
  const int g = lane >> 4, ln = lane & 15;
  const int b = blockIdx.x >> 6;
  const int h = blockIdx.x & 63;
  f32x4 acc[2][4];   // [of][wf]
#pragma unroll
  for (int of = 0; of < 2; ++of)
#pragma unroll
    for (int wf = 0; wf < 4; ++wf) acc[of][wf] = (f32x4){0.f, 0.f, 0.f, 0.f};
  f32x4 kacc = {0.f, 0.f, 0.f, 0.f};
  for (int chunk = 0; chunk < 4; ++chunk) {
    __syncthreads();
    if (t < 384) {   // halo zeros
      int dh = t >> 7, rr = t & 127;
      int cl = rr & 63, wH = (rr >> 6) ? 65 : 0;
      uint32_t bo = ((((dh * 66 + wH) << 6) + cl) << 1) ^ ((wH & 7) << 4);
      *(bf16*)((char*)sm + bo) = (bf16)0.f;
    }
    {
      const int wg = t & 15, clp = t >> 4;   // clp 0..31
      for (int dh = 0; dh < 3; ++dh) {
        int hh = h + dh - 1;
        bool ok = (hh >= 0) && (hh < 64);
        for (int p = 0; p < 2; ++p) {
          int cl = (p << 5) + clp;
          int w0 = wg << 2;
          float4 xv = make_float4(0.f, 0.f, 0.f, 0.f);
          if (ok) xv = *(const float4*)&img[((((size_t)b << 8) + (chunk << 6) + cl) * 64 + hh) * 64 + w0];
          const float xs[4] = {xv.x, xv.y, xv.z, xv.w};
#pragma unroll
          for (int q4 = 0; q4 < 4; ++q4) {
            int wH = w0 + q4 + 1;
            uint32_t bo = ((((dh * 66 + wH) << 6) + cl) << 1) ^ ((wH & 7) << 4);
            *(bf16*)((char*)sm + bo) = (bf16)xs[q4];
          }
        }
      }
    }
    __syncthreads();
#pragma unroll
    for (int ks = 0; ks < 18; ++ks) {
      const int tap = ks >> 1, clb = (ks & 1) << 5;
      const int kh = tap / 3, kw = tap - kh * 3;
      bf16x8 bfr[4];
#pragma unroll
      for (int wf = 0; wf < 4; ++wf) {
        int wH = (wf << 4) + ln + kw;
        uint32_t bo = ((((kh * 66 + wH) << 6) + clb + (g << 3)) << 1) ^ ((wH & 7) << 4);
        bfr[wf] = *(const bf16x8*)((char*)sm + bo);
      }
#pragma unroll
      for (int of = 0; of < 2; ++of) {
        bf16x8 afr = *(const bf16x8*)&W2v[(size_t)((wv << 5) + (of << 4) + ln) * 2304 +
                                          chunk * 576 + (ks << 5) + (g << 3)];
#pragma unroll
        for (int wf = 0; wf < 4; ++wf) acc[of][wf] = mfma16(afr, bfr[wf], acc[of][wf]);
      }
      if (wv < 4) {
        bf16x8 afrk = *(const bf16x8*)&W2k[(size_t)ln * 2304 + chunk * 576 + (ks << 5) + (g << 3)];
        kacc = mfma16(afrk, bfr[wv], kacc);
      }
    }
  }
  // v epilogue
#pragma unroll
  for (int of = 0; of < 2; ++of)
#pragma unroll
    for (int r = 0; r < 4; ++r) {
      int o = (wv << 5) + (of << 4) + (g << 2) + r;
      float bvv = bv[o];
#pragma unroll
      for (int wf = 0; wf < 4; ++wf) {
        int p = (h << 6) + (wf << 4) + ln;
        Vb[(((size_t)b << 8) + o) * 4096 + p] = (bf16)(acc[of][wf][r] + bvv);
      }
    }
  // k epilogue (waves 0-3, pixel quarter wf=wv)
  if (wv < 4) {
    const int p = (h << 6) + (wv << 4) + ln;
    bf16* drow = kTo + (((size_t)b << 12) + p) * 32;
#pragma unroll
    for (int r = 0; r < 4; ++r) {
      int o = (g << 2) + r;
      float val = kacc[r] + bk[o];
      bf16 hi = (bf16)val;
      drow[o] = hi;                           // A = [kh|kl]
      drow[16 + o] = (bf16)(val - (float)hi);
    }
  }
}

// ===================== attention =====================
// r11: producer/consumer wave specialization. grid 256 = (b, it 0..63), i-tile 64,
// 8 waves. Waves 0-3 = producers (f=wv): QK from K-LDS, exp2, P->LDS(dbuf), K-staging.
// Waves 4-7 = consumers (64 ch each, cb=(wv&3)*64): 2-deep ping-pong V prefetch, PV
// over all 4 f from P-LDS. Each SIMD pairs 1 producer + 1 consumer -> QK/softmax
// (VALU) overlaps PV (MFMA+VMEM+LDS) every cycle, fixing r10's phase-serial 2300-cyc
// floor. QK/exp now computed ONCE per (b,it) (r10's ch-split duplicated it 2x);
// P-LDS read traffic 128KB -> 32KB per CU-jt. Raw exp2 (no max): |s*log2e| << 127.
// batch -> XCD pair {b, b+4}. T5 setprio around consumer MFMA (role-split active).
__global__ __launch_bounds__(512, 2) void attn_kernel(
    const bf16* __restrict__ qT, const bf16* __restrict__ kT,
    const bf16* __restrict__ Vb, float* __restrict__ outp) {
  __shared__ __align__(16) char Klds[2 * 4096];   // [buf][row 64][64B] swizzled
  __shared__ __align__(16) char Plds[2 * 8192];   // [buf][f 4][ln 16][128B] swizzled
  __shared__ float lsumS[4][16];
  const int raw = blockIdx.x;          // 256
  const int b  = raw & 3;              // batch -> XCD pair {b, b+4}
  const int it = raw >> 2;             // 0..63
  const int i0 = it << 6;
  const int t = threadIdx.x;
  const int lane = t & 63, wv = t >> 6;
  const int g = lane >> 4, ln = lane & 15;
  const bool prod = (wv < 4);
  const int f = wv & 3;
  const int cb = f << 6;               // consumer: 64-channel base

  const char* kTb = (const char*)kT + (((size_t)b << 12) << 6);  // 64B rows

  // producer state
  bf16x8 bq1 = {}, bq2 = {};
  if (prod) {
    const bf16* qrow = &qT[(((size_t)b << 12) + i0 + (f << 4) + ln) * 64];
    bq1 = *(const bf16x8*)&qrow[g << 3];
    bq2 = *(const bf16x8*)&qrow[32 + (g << 3)];
  }
  float lsum = 0.f;
  const int krow = t >> 2, kc = t & 3;   // K-stage map (producers: t 0..255)
  const uint32_t kwoff = ((uint32_t)krow << 6) + ((uint32_t)(kc ^ (krow & 3)) << 4);

  // consumer state
  f32x4 acc[4][4];   // [cf][f]
#pragma unroll
  for (int cf = 0; cf < 4; ++cf)
#pragma unroll
    for (int ff = 0; ff < 4; ++ff) acc[cf][ff] = (f32x4){0.f, 0.f, 0.f, 0.f};
  bf16x8 avA[8], avB[8];   // ping-pong V prefetch [ks*4+cf]; static idx via unroll

  // prologue: producers stage K(0) -> buf0
  if (prod)
    *(f32x4*)(Klds + kwoff) = *(const f32x4*)(kTb + ((size_t)krow << 6) + (kc << 4));
  __syncthreads();

  for (int m = 0; m < 32; ++m) {
    const int jtA = m << 1;           // even jt
    // ---------- sub-iter A ----------
    if (prod) {
      f32x4 s[4];
#pragma unroll
      for (int jf = 0; jf < 4; ++jf) {
        const int row = (jf << 4) + ln;
        bf16x8 ak = *(const bf16x8*)(Klds + ((uint32_t)row << 6) + ((uint32_t)(g ^ (row & 3)) << 4));
        f32x4 z = {0.f, 0.f, 0.f, 0.f};
        s[jf] = mfma16(ak, bq2, mfma16(ak, bq1, z));
      }
#pragma unroll
      for (int jf = 0; jf < 4; ++jf) {
        union { bf16 h[4]; unsigned long long v; } pk;
#pragma unroll
        for (int r = 0; r < 4; ++r) {
          float pv = __builtin_amdgcn_exp2f(s[jf][r]);
          lsum += pv;
          pk.h[r] = (bf16)pv;
        }
        uint32_t bo = (((uint32_t)f << 11) + ((uint32_t)ln << 7) + (jf << 5) + (g << 3)) ^ ((ln & 7) << 4);
        *(unsigned long long*)(Plds + bo) = pk.v;            // P buf0
      }
      // stage K(jtA+1) -> buf1
      *(f32x4*)(Klds + 4096 + kwoff) =
          *(const f32x4*)(kTb + ((size_t)(((jtA + 1) << 6) + krow) << 6) + (kc << 4));
    } else {
      const int j0 = jtA << 6;
#pragma unroll
      for (int ks = 0; ks < 2; ++ks)
#pragma unroll
        for (int cf = 0; cf < 4; ++cf)
          avB[ks * 4 + cf] = *(const bf16x8*)&Vb[(((size_t)b << 8) + cb + (cf << 4) + ln) * 4096 +
                                                 j0 + (ks << 5) + (g << 3)];
      if (m > 0) {   // PV(jtA-1): P buf1, V in avA
        __builtin_amdgcn_s_setprio(1);
#pragma unroll
        for (int ks = 0; ks < 2; ++ks) {
          bf16x8 bp[4];
#pragma unroll
          for (int ff = 0; ff < 4; ++ff) {
            uint32_t bo = (8192u + ((uint32_t)ff << 11) + ((uint32_t)ln << 7) + (ks << 6) + (g << 4)) ^ ((ln & 7) << 4);
            bp[ff] = *(const bf16x8*)(Plds + bo);
          }
#pragma unroll
          for (int cf = 0; cf < 4; ++cf)
#pragma unroll
            for (int ff = 0; ff < 4; ++ff)
              acc[cf][ff] = mfma16(avA[ks * 4 + cf], bp[ff], acc[cf][ff]);
        }
        __builtin_amdgcn_s_setprio(0);
      }
    }
    __syncthreads();
    // ---------- sub-iter B ----------
    const int jtB = jtA + 1;          // odd jt
    if (prod) {
      f32x4 s[4];
#pragma unroll
      for (int jf = 0; jf < 4; ++jf) {
        const int row = (jf << 4) + ln;
        bf16x8 ak = *(const bf16x8*)(Klds + 4096 + ((uint32_t)row << 6) + ((uint32_t)(g ^ (row & 3)) << 4));
        f32x4 z = {0.f, 0.f, 0.f, 0.f};
        s[jf] = mfma16(ak, bq2, mfma16(ak, bq1, z));
      }
#pragma unroll
      for (int jf = 0; jf < 4; ++jf) {
        union { bf16 h[4]; unsigned long long v; } pk;
#pragma unroll
        for (int r = 0; r < 4; ++r) {
          float pv = __builtin_amdgcn_exp2f(s[jf][r]);
          lsum += pv;
          pk.h[r] = (bf16)pv;
        }
        uint32_t bo = (8192u + ((uint32_t)f << 11) + ((uint32_t)ln << 7) + (jf << 5) + (g << 3)) ^ ((ln & 7) << 4);
        *(unsigned long long*)(Plds + bo) = pk.v;            // P buf1
      }
      if (m < 31)   // stage K(jtB+1) -> buf0
        *(f32x4*)(Klds + kwoff) =
            *(const f32x4*)(kTb + ((size_t)(((jtB + 1) << 6) + krow) << 6) + (kc << 4));
    } else {
      const int j0 = jtB << 6;
#pragma unroll
      for (int ks = 0; ks < 2; ++ks)
#pragma unroll
        for (int cf = 0; cf < 4; ++cf)
          avA[ks * 4 + cf] = *(const bf16x8*)&Vb[(((size_t)b << 8) + cb + (cf << 4) + ln) * 4096 +
                                                 j0 + (ks << 5) + (g << 3)];
      // PV(jtA): P buf0, V in avB
      __builtin_amdgcn_s_setprio(1);
#pragma unroll
      for (int ks = 0; ks < 2; ++ks) {
        bf16x8 bp[4];
#pragma unroll
        for (int ff = 0; ff < 4; ++ff) {
          uint32_t bo = (((uint32_t)ff << 11) + ((uint32_t)ln << 7) + (ks << 6) + (g << 4)) ^ ((ln & 7) << 4);
          bp[ff] = *(const bf16x8*)(Plds + bo);
        }
#pragma unroll
        for (int cf = 0; cf < 4; ++cf)
#pragma unroll
          for (int ff = 0; ff < 4; ++ff)
            acc[cf][ff] = mfma16(avB[ks * 4 + cf], bp[ff], acc[cf][ff]);
      }
      __builtin_amdgcn_s_setprio(0);
    }
    __syncthreads();
  }
  // epilogue: producers publish lsum; consumers do final PV(63) (P buf1, avA)
  if (prod) {
    float l = lsum;
    l += __shfl_xor(l, 16, 64);
    l += __shfl_xor(l, 32, 64);
    if (g == 0) lsumS[f][ln] = l;
  } else {
#pragma unroll
    for (int ks = 0; ks < 2; ++ks) {
      bf16x8 bp[4];
#pragma unroll
      for (int ff = 0; ff < 4; ++ff) {
        uint32_t bo = (8192u + ((uint32_t)ff << 11) + ((uint32_t)ln << 7) + (ks << 6) + (g << 4)) ^ ((ln & 7) << 4);
        bp[ff] = *(const bf16x8*)(Plds + bo);
      }
#pragma unroll
      for (int cf = 0; cf < 4; ++cf)
#pragma unroll
        for (int ff = 0; ff < 4; ++ff)
          acc[cf][ff] = mfma16(avA[ks * 4 + cf], bp[ff], acc[cf][ff]);
    }
  }
  __syncthreads();
  if (!prod) {
#pragma unroll
    for (int ff = 0; ff < 4; ++ff) {
      float rdiv = 1.f / lsumS[ff][ln];
      const int i = i0 + (ff << 4) + ln;
#pragma unroll
      for (int cf = 0; cf < 4; ++cf)
#pragma unroll
        for (int r = 0; r < 4; ++r) {
          int c = cb + (cf << 4) + (g << 2) + r;
          outp[(((size_t)b << 8) + c) * 4096 + i] = acc[cf][ff][r] * rdiv;
        }
    }
  }
}

// ===================== launch =====================
extern "C" void kernel_launch(void* const* d_in, const int* in_sizes, int n_in,
                              void* d_out, int out_size, void* d_ws, size_t ws_size,
                              hipStream_t stream) {
  const float* x  = (const float*)d_in[0];
  const float* y  = (const float*)d_in[1];
  const float* wq = (const float*)d_in[2];
  const float* bq = (const float*)d_in[3];
  const float* wk = (const float*)d_in[4];
  const float* bk = (const float*)d_in[5];
  const float* wv = (const float*)d_in[6];
  const float* bv = (const float*)d_in[7];
  float* out = (float*)d_out;

  char* ws = (char*)d_ws;
  bf16* qT  = (bf16*)(ws);
  bf16* kT  = (bf16*)(ws + (2u << 20));
  bf16* Vb  = (bf16*)(ws + (3u << 20));
  bf16* W2v = (bf16*)(ws + (11u << 20));
  bf16* W2q = (bf16*)(ws + (11u << 20) + 1179648u);
  bf16* W2k = (bf16*)(ws + (11u << 20) + 1179648u + 73728u);

  pack_all_kernel<<<2592, 256, 0, stream>>>(wv, wq, wk, W2v, W2q, W2k);
  conv_q_kernel<<<256, 256, 0, stream>>>(x, W2q, bq, qT);
  conv_vk_kernel<<<256, 512, 0, stream>>>(y, W2v, W2k, bv, bk, Vb, kT);
  attn_kernel<<<256, 512, 0, stream>>>(qT, kT, Vb, out);
}

// Round 12
// 162.776 us; speedup vs baseline: 1.5316x; 1.5316x over previous
//
#include <hip/hip_runtime.h>
#include <stdint.h>

// B=4, C=256, H=W=64, N=4096, CQK=16, Ktot=C*9=2304
// ws layout:
//   qT  [4][4096][64] bf16   @ 0        (2 MiB)  slots0-31=[qh|qh], 32-63=[ql|0], q pre-scaled by log2(e)
//   kT  [4][4096][32] bf16   @ 2 MiB    (1 MiB)  slots0-15=kh, 16-31=kl (residual)
//   Vb  [4][256][4096] bf16  @ 3 MiB    (8 MiB)
//   W2v [256][2304] bf16     @ 11 MiB   (1152 KiB)   k-order: (ci>>6)*576 + tap*64 + (ci&63)
//   W2q [16][2304]  bf16     @ +1179648 (72 KiB)
//   W2k [16][2304]  bf16     @ +73728   (72 KiB)

typedef __bf16 bf16;
typedef bf16 bf16x8 __attribute__((ext_vector_type(8)));
typedef float f32x4 __attribute__((ext_vector_type(4)));

#define DEV static __device__ __forceinline__

DEV f32x4 mfma16(bf16x8 a, bf16x8 b, f32x4 c) {
  return __builtin_amdgcn_mfma_f32_16x16x32_bf16(a, b, c, 0, 0, 0);
}

// ===================== weight pack (all 3 tensors, one launch) =====================
__global__ void pack_all_kernel(const float* __restrict__ wv, const float* __restrict__ wq,
                                const float* __restrict__ wk, bf16* __restrict__ W2v,
                                bf16* __restrict__ W2q, bf16* __restrict__ W2k) {
  int idx = blockIdx.x * 256 + threadIdx.x;
  if (idx >= 663552) return;
  const float* src;
  bf16* dst;
  int rel;
  if (idx < 589824)      { src = wv; dst = W2v; rel = idx; }
  else if (idx < 626688) { src = wq; dst = W2q; rel = idx - 589824; }
  else                   { src = wk; dst = W2k; rel = idx - 626688; }
  int o = rel / 2304, r = rel - o * 2304;
  int ci = r / 9, tap = r - ci * 9;
  int kk = (ci >> 6) * 576 + tap * 64 + (ci & 63);
  dst[o * 2304 + kk] = (bf16)src[rel];
}

// ===================== conv staging (shared) =====================
// LDS tile: [dh 0..2][wHalo 0..65][cl 0..63] bf16, byte addr ^ ((wH&7)<<4) swizzle.
DEV void stage_chunk(bf16* sm, const float* __restrict__ img, int b, int h, int ci0, int t) {
  for (int idx = t; idx < 384; idx += 256) {
    int dh = idx >> 7, rr = idx & 127;
    int cl = rr & 63, wH = (rr >> 6) ? 65 : 0;
    uint32_t bo = ((((dh * 66 + wH) << 6) + cl) << 1) ^ ((wH & 7) << 4);
    *(bf16*)((char*)sm + bo) = (bf16)0.f;
  }
  const int wg = t & 15, clp = t >> 4;
  for (int dh = 0; dh < 3; ++dh) {
    int hh = h + dh - 1;
    bool ok = (hh >= 0) && (hh < 64);
    for (int p = 0; p < 4; ++p) {
      int cl = (p << 4) + clp;
      int w0 = wg << 2;
      float4 xv = make_float4(0.f, 0.f, 0.f, 0.f);
      if (ok) xv = *(const float4*)&img[((((size_t)b << 8) + ci0 + cl) * 64 + hh) * 64 + w0];
      const float xs[4] = {xv.x, xv.y, xv.z, xv.w};
#pragma unroll
      for (int q4 = 0; q4 < 4; ++q4) {
        int wH = w0 + q4 + 1;
        uint32_t bo = ((((dh * 66 + wH) << 6) + cl) << 1) ^ ((wH & 7) << 4);
        *(bf16*)((char*)sm + bo) = (bf16)xs[q4];
      }
    }
  }
}

// ===================== conv q + k fused (O=16) =====================
// grid 512: blocks 0-255 q-mode (img=x, scale log2e, qT 64-wide), 256-511 k-mode (img=y, kT 32-wide)
__global__ __launch_bounds__(256) void conv_qk_kernel(
    const float* __restrict__ x, const float* __restrict__ y,
    const bf16* __restrict__ W2q, const bf16* __restrict__ W2k,
    const float* __restrict__ bq, const float* __restrict__ bk,
    bf16* __restrict__ qT, bf16* __restrict__ kT) {
  __shared__ __align__(16) bf16 sm[3 * 66 * 64];
  const int mode = blockIdx.x >> 8;       // 0=q, 1=k
  const float* img = mode ? y : x;
  const bf16* W2 = mode ? W2k : W2q;
  const float* bias = mode ? bk : bq;
  const int bi = blockIdx.x & 255;
  const int t = threadIdx.x;
  const int lane = t & 63, wv = t >> 6;
  const int g = lane >> 4, ln = lane & 15;
  const int b = bi >> 6;
  const int h = bi & 63;
  f32x4 acc = {0.f, 0.f, 0.f, 0.f};
  for (int chunk = 0; chunk < 4; ++chunk) {
    __syncthreads();
    stage_chunk(sm, img, b, h, chunk << 6, t);
    __syncthreads();
#pragma unroll
    for (int ks = 0; ks < 18; ++ks) {
      const int tap = ks >> 1, clb = (ks & 1) << 5;
      const int kh = tap / 3, kw = tap - kh * 3;
      const int wH = (wv << 4) + ln + kw;
      uint32_t bo = ((((kh * 66 + wH) << 6) + clb + (g << 3)) << 1) ^ ((wH & 7) << 4);
      bf16x8 bfr = *(const bf16x8*)((char*)sm + bo);
      bf16x8 afr = *(const bf16x8*)&W2[(size_t)ln * 2304 + chunk * 576 + (ks << 5) + (g << 3)];
      acc = mfma16(afr, bfr, acc);
    }
  }
  const int p = (h << 6) + (wv << 4) + ln;
#pragma unroll
  for (int r = 0; r < 4; ++r) {
    int o = (g << 2) + r;
    float val = acc[r] + bias[o];
    if (mode == 0) {
      val *= 1.4426950408889634f;              // log2(e): softmax via exp2
      bf16* drow = qT + (((size_t)b << 12) + p) * 64;
      bf16 hi = (bf16)val;
      drow[o] = hi;
      drow[16 + o] = hi;                       // B1 = [qh|qh]
      drow[32 + o] = (bf16)(val - (float)hi);  // B2 = [ql|0]
      drow[48 + o] = (bf16)0.f;
    } else {
      bf16* drow = kT + (((size_t)b << 12) + p) * 32;
      bf16 hi = (bf16)val;
      drow[o] = hi;                            // A = [kh|kl]
      drow[16 + o] = (bf16)(val - (float)hi);
    }
  }
}

// ===================== conv v (O=256) =====================
__global__ __launch_bounds__(256) void conv_v_kernel(
    const float* __restrict__ img, const bf16* __restrict__ W2,
    const float* __restrict__ bias, bf16* __restrict__ dst) {
  __shared__ __align__(16) bf16 sm[3 * 66 * 64];
  const int t = threadIdx.x;
  const int lane = t & 63, wv = t >> 6;
  const int g = lane >> 4, ln = lane & 15;
  const int raw = blockIdx.x;
  const int b = raw >> 7;
  const int h = (raw >> 1) & 63;
  const int oh = raw & 1;
  const int obase = (oh << 7) + (wv << 5);
  f32x4 acc[2][4];
#pragma unroll
  for (int of = 0; of < 2; ++of)
#pragma unroll
    for (int wf = 0; wf < 4; ++wf) acc[of][wf] = (f32x4){0.f, 0.f, 0.f, 0.f};
  for (int chunk = 0; chunk < 4; ++chunk) {
    __syncthreads();
    stage_chunk(sm, img, b, h, chunk << 6, t);
    __syncthreads();
#pragma unroll
    for (int ks = 0; ks < 18; ++ks) {
      const int tap = ks >> 1, clb = (ks & 1) << 5;
      const int kh = tap / 3, kw = tap - kh * 3;
      bf16x8 bfr[4];
#pragma unroll
      for (int wf = 0; wf < 4; ++wf) {
        int wH = (wf << 4) + ln + kw;
        uint32_t bo = ((((kh * 66 + wH) << 6) + clb + (g << 3)) << 1) ^ ((wH & 7) << 4);
        bfr[wf] = *(const bf16x8*)((char*)sm + bo);
      }
#pragma unroll
      for (int of = 0; of < 2; ++of) {
        bf16x8 afr = *(const bf16x8*)&W2[(size_t)(obase + (of << 4) + ln) * 2304 +
                                         chunk * 576 + (ks << 5) + (g << 3)];
#pragma unroll
        for (int wf = 0; wf < 4; ++wf) acc[of][wf] = mfma16(afr, bfr[wf], acc[of][wf]);
      }
    }
  }
#pragma unroll
  for (int of = 0; of < 2; ++of)
#pragma unroll
    for (int r = 0; r < 4; ++r) {
      int o = obase + (of << 4) + (g << 2) + r;
      float bvv = bias[o];
#pragma unroll
      for (int wf = 0; wf < 4; ++wf) {
        int p = (h << 6) + (wf << 4) + ln;
        dst[(((size_t)b << 8) + o) * 4096 + p] = (bf16)(acc[of][wf][r] + bvv);
      }
    }
}

// ===================== attention =====================
// r11 structure (kept; measured ~45-50 µs): producer/consumer wave specialization.
// grid 256 = (b, it 0..63), i-tile 64, 8 waves. Waves 0-3 = producers (f=wv): QK from
// K-LDS, exp2, P->LDS(dbuf), K-staging. Waves 4-7 = consumers (64 ch each): 2-deep
// ping-pong V prefetch, PV over all 4 f from P-LDS. 1 producer + 1 consumer per SIMD
// -> QK/softmax (VALU) overlaps PV (MFMA+VMEM+LDS). Raw exp2 (no max). batch -> XCD
// pair {b, b+4}. T5 setprio around consumer MFMA.
__global__ __launch_bounds__(512, 2) void attn_kernel(
    const bf16* __restrict__ qT, const bf16* __restrict__ kT,
    const bf16* __restrict__ Vb, float* __restrict__ outp) {
  __shared__ __align__(16) char Klds[2 * 4096];   // [buf][row 64][64B] swizzled
  __shared__ __align__(16) char Plds[2 * 8192];   // [buf][f 4][ln 16][128B] swizzled
  __shared__ float lsumS[4][16];
  const int raw = blockIdx.x;          // 256
  const int b  = raw & 3;              // batch -> XCD pair {b, b+4}
  const int it = raw >> 2;             // 0..63
  const int i0 = it << 6;
  const int t = threadIdx.x;
  const int lane = t & 63, wv = t >> 6;
  const int g = lane >> 4, ln = lane & 15;
  const bool prod = (wv < 4);
  const int f = wv & 3;
  const int cb = f << 6;               // consumer: 64-channel base

  const char* kTb = (const char*)kT + (((size_t)b << 12) << 6);  // 64B rows

  // producer state
  bf16x8 bq1 = {}, bq2 = {};
  if (prod) {
    const bf16* qrow = &qT[(((size_t)b << 12) + i0 + (f << 4) + ln) * 64];
    bq1 = *(const bf16x8*)&qrow[g << 3];
    bq2 = *(const bf16x8*)&qrow[32 + (g << 3)];
  }
  float lsum = 0.f;
  const int krow = t >> 2, kc = t & 3;   // K-stage map (producers: t 0..255)
  const uint32_t kwoff = ((uint32_t)krow << 6) + ((uint32_t)(kc ^ (krow & 3)) << 4);

  // consumer state
  f32x4 acc[4][4];   // [cf][f]
#pragma unroll
  for (int cf = 0; cf < 4; ++cf)
#pragma unroll
    for (int ff = 0; ff < 4; ++ff) acc[cf][ff] = (f32x4){0.f, 0.f, 0.f, 0.f};
  bf16x8 avA[8], avB[8];   // ping-pong V prefetch [ks*4+cf]; static idx via unroll

  // prologue: producers stage K(0) -> buf0
  if (prod)
    *(f32x4*)(Klds + kwoff) = *(const f32x4*)(kTb + ((size_t)krow << 6) + (kc << 4));
  __syncthreads();

  for (int m = 0; m < 32; ++m) {
    const int jtA = m << 1;           // even jt
    // ---------- sub-iter A ----------
    if (prod) {
      f32x4 s[4];
#pragma unroll
      for (int jf = 0; jf < 4; ++jf) {
        const int row = (jf << 4) + ln;
        bf16x8 ak = *(const bf16x8*)(Klds + ((uint32_t)row << 6) + ((uint32_t)(g ^ (row & 3)) << 4));
        f32x4 z = {0.f, 0.f, 0.f, 0.f};
        s[jf] = mfma16(ak, bq2, mfma16(ak, bq1, z));
      }
#pragma unroll
      for (int jf = 0; jf < 4; ++jf) {
        union { bf16 h[4]; unsigned long long v; } pk;
#pragma unroll
        for (int r = 0; r < 4; ++r) {
          float pv = __builtin_amdgcn_exp2f(s[jf][r]);
          lsum += pv;
          pk.h[r] = (bf16)pv;
        }
        uint32_t bo = (((uint32_t)f << 11) + ((uint32_t)ln << 7) + (jf << 5) + (g << 3)) ^ ((ln & 7) << 4);
        *(unsigned long long*)(Plds + bo) = pk.v;            // P buf0
      }
      // stage K(jtA+1) -> buf1
      *(f32x4*)(Klds + 4096 + kwoff) =
          *(const f32x4*)(kTb + ((size_t)(((jtA + 1) << 6) + krow) << 6) + (kc << 4));
    } else {
      const int j0 = jtA << 6;
#pragma unroll
      for (int ks = 0; ks < 2; ++ks)
#pragma unroll
        for (int cf = 0; cf < 4; ++cf)
          avB[ks * 4 + cf] = *(const bf16x8*)&Vb[(((size_t)b << 8) + cb + (cf << 4) + ln) * 4096 +
                                                 j0 + (ks << 5) + (g << 3)];
      if (m > 0) {   // PV(jtA-1): P buf1, V in avA
        __builtin_amdgcn_s_setprio(1);
#pragma unroll
        for (int ks = 0; ks < 2; ++ks) {
          bf16x8 bp[4];
#pragma unroll
          for (int ff = 0; ff < 4; ++ff) {
            uint32_t bo = (8192u + ((uint32_t)ff << 11) + ((uint32_t)ln << 7) + (ks << 6) + (g << 4)) ^ ((ln & 7) << 4);
            bp[ff] = *(const bf16x8*)(Plds + bo);
          }
#pragma unroll
          for (int cf = 0; cf < 4; ++cf)
#pragma unroll
            for (int ff = 0; ff < 4; ++ff)
              acc[cf][ff] = mfma16(avA[ks * 4 + cf], bp[ff], acc[cf][ff]);
        }
        __builtin_amdgcn_s_setprio(0);
      }
    }
    __syncthreads();
    // ---------- sub-iter B ----------
    const int jtB = jtA + 1;          // odd jt
    if (prod) {
      f32x4 s[4];
#pragma unroll
      for (int jf = 0; jf < 4; ++jf) {
        const int row = (jf << 4) + ln;
        bf16x8 ak = *(const bf16x8*)(Klds + 4096 + ((uint32_t)row << 6) + ((uint32_t)(g ^ (row & 3)) << 4));
        f32x4 z = {0.f, 0.f, 0.f, 0.f};
        s[jf] = mfma16(ak, bq2, mfma16(ak, bq1, z));
      }
#pragma unroll
      for (int jf = 0; jf < 4; ++jf) {
        union { bf16 h[4]; unsigned long long v; } pk;
#pragma unroll
        for (int r = 0; r < 4; ++r) {
          float pv = __builtin_amdgcn_exp2f(s[jf][r]);
          lsum += pv;
          pk.h[r] = (bf16)pv;
        }
        uint32_t bo = (8192u + ((uint32_t)f << 11) + ((uint32_t)ln << 7) + (jf << 5) + (g << 3)) ^ ((ln & 7) << 4);
        *(unsigned long long*)(Plds + bo) = pk.v;            // P buf1
      }
      if (m < 31)   // stage K(jtB+1) -> buf0
        *(f32x4*)(Klds + kwoff) =
            *(const f32x4*)(kTb + ((size_t)(((jtB + 1) << 6) + krow) << 6) + (kc << 4));
    } else {
      const int j0 = jtB << 6;
#pragma unroll
      for (int ks = 0; ks < 2; ++ks)
#pragma unroll
        for (int cf = 0; cf < 4; ++cf)
          avA[ks * 4 + cf] = *(const bf16x8*)&Vb[(((size_t)b << 8) + cb + (cf << 4) + ln) * 4096 +
                                                 j0 + (ks << 5) + (g << 3)];
      // PV(jtA): P buf0, V in avB
      __builtin_amdgcn_s_setprio(1);
#pragma unroll
      for (int ks = 0; ks < 2; ++ks) {
        bf16x8 bp[4];
#pragma unroll
        for (int ff = 0; ff < 4; ++ff) {
          uint32_t bo = (((uint32_t)ff << 11) + ((uint32_t)ln << 7) + (ks << 6) + (g << 4)) ^ ((ln & 7) << 4);
          bp[ff] = *(const bf16x8*)(Plds + bo);
        }
#pragma unroll
        for (int cf = 0; cf < 4; ++cf)
#pragma unroll
          for (int ff = 0; ff < 4; ++ff)
            acc[cf][ff] = mfma16(avB[ks * 4 + cf], bp[ff], acc[cf][ff]);
      }
      __builtin_amdgcn_s_setprio(0);
    }
    __syncthreads();
  }
  // epilogue: producers publish lsum; consumers do final PV(63) (P buf1, avA)
  if (prod) {
    float l = lsum;
    l += __shfl_xor(l, 16, 64);
    l += __shfl_xor(l, 32, 64);
    if (g == 0) lsumS[f][ln] = l;
  } else {
#pragma unroll
    for (int ks = 0; ks < 2; ++ks) {
      bf16x8 bp[4];
#pragma unroll
      for (int ff = 0; ff < 4; ++ff) {
        uint32_t bo = (8192u + ((uint32_t)ff << 11) + ((uint32_t)ln << 7) + (ks << 6) + (g << 4)) ^ ((ln & 7) << 4);
        bp[ff] = *(const bf16x8*)(Plds + bo);
      }
#pragma unroll
      for (int cf = 0; cf < 4; ++cf)
#pragma unroll
        for (int ff = 0; ff < 4; ++ff)
          acc[cf][ff] = mfma16(avA[ks * 4 + cf], bp[ff], acc[cf][ff]);
    }
  }
  __syncthreads();
  if (!prod) {
#pragma unroll
    for (int ff = 0; ff < 4; ++ff) {
      float rdiv = 1.f / lsumS[ff][ln];
      const int i = i0 + (ff << 4) + ln;
#pragma unroll
      for (int cf = 0; cf < 4; ++cf)
#pragma unroll
        for (int r = 0; r < 4; ++r) {
          int c = cb + (cf << 4) + (g << 2) + r;
          outp[(((size_t)b << 8) + c) * 4096 + i] = acc[cf][ff][r] * rdiv;
        }
    }
  }
}

// ===================== launch =====================
extern "C" void kernel_launch(void* const* d_in, const int* in_sizes, int n_in,
                              void* d_out, int out_size, void* d_ws, size_t ws_size,
                              hipStream_t stream) {
  const float* x  = (const float*)d_in[0];
  const float* y  = (const float*)d_in[1];
  const float* wq = (const float*)d_in[2];
  const float* bq = (const float*)d_in[3];
  const float* wk = (const float*)d_in[4];
  const float* bk = (const float*)d_in[5];
  const float* wv = (const float*)d_in[6];
  const float* bv = (const float*)d_in[7];
  float* out = (float*)d_out;

  char* ws = (char*)d_ws;
  bf16* qT  = (bf16*)(ws);
  bf16* kT  = (bf16*)(ws + (2u << 20));
  bf16* Vb  = (bf16*)(ws + (3u << 20));
  bf16* W2v = (bf16*)(ws + (11u << 20));
  bf16* W2q = (bf16*)(ws + (11u << 20) + 1179648u);
  bf16* W2k = (bf16*)(ws + (11u << 20) + 1179648u + 73728u);

  pack_all_kernel<<<2592, 256, 0, stream>>>(wv, wq, wk, W2v, W2q, W2k);
  conv_qk_kernel<<<512, 256, 0, stream>>>(x, y, W2q, W2k, bq, bk, qT, kT);
  conv_v_kernel<<<512, 256, 0, stream>>>(y, W2v, bv, Vb);
  attn_kernel<<<256, 512, 0, stream>>>(qT, kT, Vb, out);
}